// Round 7
// baseline (48.648 us; speedup 1.0000x reference)
//
#include <hip/hip_runtime.h>
#include <hip/hip_fp16.h>

#define BSZ 2
#define CIN 32
#define COUT 64
#define DD_ 8
#define HH_ 48
#define WW_ 48
#define KK 27
#define HWs (HH_*WW_)
#define DHW (DD_*HH_*WW_)
#define NBLK (BSZ*DD_*HH_)    // 768 rows
#define KG 9                  // k's per block (3 k-groups)
#define NT 768                // 12 waves = 12 output tiles

typedef __attribute__((ext_vector_type(8))) _Float16 half8;
typedef __attribute__((ext_vector_type(4))) float f32x4;

// out[b][co][d][h][w] = bias[co]  (accumulation base for atomic epilogue)
__global__ void init_out(const float* __restrict__ bias, float* __restrict__ out) {
    int o4 = blockIdx.x * 256 + threadIdx.x;          // float4 index
    if (o4 >= BSZ * COUT * DHW / 4) return;
    int o = o4 * 4;
    float bv = bias[(o / DHW) & (COUT - 1)];
    float4 v = {bv, bv, bv, bv};
    *(float4*)(out + o) = v;
}

// prep: blocks [0,NBLK): x f32 [B][Cin][D][H][W] -> xT f16 [B][D][H][W][Cin]
//       blocks [NBLK, NBLK+216): w f32 (Cout,Cin,K) -> wf f16 lane-linear A-frags
//       wf[((k*4 + c)*64 + l)*8 + j] = w[c*16+(l&15)][(l>>4)*8+j][k]
__global__ void prep(const float* __restrict__ x, const float* __restrict__ wsrc,
                     _Float16* __restrict__ xT, _Float16* __restrict__ wf) {
    __shared__ float tile[CIN][WW_];
    int blk = blockIdx.x;
    if (blk < NBLK) {
        int h = blk % HH_;
        int t0 = blk / HH_;
        int d = t0 % DD_;
        int b = t0 / DD_;
        int base = d * HWs + h * WW_;
        for (int e = threadIdx.x; e < CIN * WW_; e += 256) {
            int ci = e / WW_, w = e - ci * WW_;
            tile[ci][w] = x[(size_t)(b * CIN + ci) * DHW + base + w];
        }
        __syncthreads();
        for (int e = threadIdx.x; e < CIN * WW_; e += 256) {
            int w = e >> 5, ci = e & 31;
            xT[(size_t)(b * DHW + base + w) * CIN + ci] = (_Float16)tile[ci][w];
        }
    } else {
        int idx = (blk - NBLK) * 256 + threadIdx.x;
        if (idx < KK * 4 * 64 * 8) {
            int j = idx & 7, l = (idx >> 3) & 63, c = (idx >> 9) & 3, k = idx >> 11;
            int co = c * 16 + (l & 15), ci = (l >> 4) * 8 + j;
            wf[idx] = (_Float16)wsrc[(co * CIN + ci) * KK + k];
        }
    }
}

template<int USE_XT>
__launch_bounds__(NT, 6)
__global__ void dcn3d(const float* __restrict__ x, const _Float16* __restrict__ xT,
                      const float* __restrict__ off, const float* __restrict__ msk,
                      const float* __restrict__ wsrc, const _Float16* __restrict__ wf,
                      float* __restrict__ out) {
    int blk = blockIdx.x;
    int kg  = blk / NBLK;                 // k-group 0..2
    int row = blk - kg * NBLK;
    int h = row % HH_;
    int t0 = row / HH_;
    int d = t0 % DD_;
    int b = t0 / DD_;

    // S tile in MFMA-B-fragment order: granule = (kl*3 + T)*64 + g*16 + wl
    __shared__ half8 Sh[KG * 3 * 64];     // 27648 B

    int tid = threadIdx.x;
    int lane = tid & 63;
    int wid = tid >> 6;
    int spb = d * HWs + h * WW_;

    const _Float16* xTb = xT + (size_t)b * DHW * CIN;
    const float* xb = x + (size_t)b * CIN * DHW;

    // ---- sampling: task = (point, granule); 4x16B gathers per task, 1 barrier total ----
#pragma unroll
    for (int i = 0; i < 3; ++i) {
        int t = tid + i * NT;
        if (t < KG * 48 * 4) {
            int p = t >> 2, g = t & 3;
            int kl = p / 48;
            int w  = p - kl * 48;
            int k  = kg * KG + kl;
            int kd = k / 9, kh2 = (k / 3) % 3, kw2 = k % 3;
            int dpos = d + kd - 1;
            bool vd = (dpos >= 0) && (dpos < DD_);
            int didx = min(max(dpos, 0), DD_ - 1);
            int rb = didx * HWs;
            int sp = spb + w;
            float oh = off[(b * (2 * KK) + 2 * k) * DHW + sp];
            float ow = off[(b * (2 * KK) + 2 * k + 1) * DHW + sp];
            float m  = msk[(b * KK + k) * DHW + sp];
            float vm = vd ? m : 0.f;
            float hhf = (float)(kh2 + h - 1) + oh;
            float wwf = (float)(kw2 + w - 1) + ow;
            float h0f = floorf(hhf), w0f = floorf(wwf);
            float lh = hhf - h0f, lw = wwf - w0f;
            int h0 = (int)h0f, w0 = (int)w0f, h1 = h0 + 1, w1 = w0 + 1;
            bool ih0 = (h0 >= 0) && (h0 < HH_), ih1 = (h1 >= 0) && (h1 < HH_);
            bool iw0 = (w0 >= 0) && (w0 < WW_), iw1 = (w1 >= 0) && (w1 < WW_);
            int h0c = min(max(h0, 0), HH_ - 1), h1c = min(max(h1, 0), HH_ - 1);
            int w0c = min(max(w0, 0), WW_ - 1), w1c = min(max(w1, 0), WW_ - 1);
            float f00 = (ih0 && iw0) ? (1.f - lh) * (1.f - lw) * vm : 0.f;
            float f01 = (ih0 && iw1) ? (1.f - lh) * lw * vm : 0.f;
            float f10 = (ih1 && iw0) ? lh * (1.f - lw) * vm : 0.f;
            float f11 = (ih1 && iw1) ? lh * lw * vm : 0.f;
            int sp00 = rb + h0c * WW_ + w0c;
            int sp01 = rb + h0c * WW_ + w1c;
            int sp10 = rb + h1c * WW_ + w0c;
            int sp11 = rb + h1c * WW_ + w1c;
            int sb = (kl * 3 + (w >> 4)) * 64 + g * 16 + (w & 15);
            if (USE_XT) {
                const _Float16* bp = xTb + g * 8;
                half8 c00 = *(const half8*)(bp + ((size_t)sp00 << 5));
                half8 c01 = *(const half8*)(bp + ((size_t)sp01 << 5));
                half8 c10 = *(const half8*)(bp + ((size_t)sp10 << 5));
                half8 c11 = *(const half8*)(bp + ((size_t)sp11 << 5));
                _Float16 e00 = (_Float16)f00, e01 = (_Float16)f01;
                _Float16 e10 = (_Float16)f10, e11 = (_Float16)f11;
                half8 v00 = {e00,e00,e00,e00,e00,e00,e00,e00};
                half8 v01 = {e01,e01,e01,e01,e01,e01,e01,e01};
                half8 v10 = {e10,e10,e10,e10,e10,e10,e10,e10};
                half8 v11 = {e11,e11,e11,e11,e11,e11,e11,e11};
                Sh[sb] = c00 * v00 + c01 * v01 + c10 * v10 + c11 * v11;
            } else {
                half8 cv;
#pragma unroll
                for (int j = 0; j < 8; ++j) {
                    const float* xp = xb + (size_t)(g * 8 + j) * DHW;
                    float v = f00 * xp[sp00] + f01 * xp[sp01]
                            + f10 * xp[sp10] + f11 * xp[sp11];
                    cv[j] = (_Float16)v;
                }
                Sh[sb] = cv;
            }
        }
    }
    __syncthreads();

    // ---- GEMM: wave (cstrip, T) tile, 9 MFMAs ----
    int cstrip = wid & 3;
    int T = wid >> 2;
    f32x4 acc = {0.f, 0.f, 0.f, 0.f};
#pragma unroll
    for (int kl = 0; kl < KG; ++kl) {
        int k = kg * KG + kl;
        half8 a;
        if (USE_XT) {
            a = *(const half8*)(wf + ((k * 4 + cstrip) * 64 + lane) * 8);
        } else {
            int co = cstrip * 16 + (lane & 15);
            int ci0 = (lane >> 4) * 8;
#pragma unroll
            for (int j = 0; j < 8; ++j)
                a[j] = (_Float16)wsrc[(co * CIN + ci0 + j) * KK + k];
        }
        half8 bfr = Sh[(kl * 3 + T) * 64 + (lane >> 4) * 16 + (lane & 15)];
        acc = __builtin_amdgcn_mfma_f32_16x16x32_f16(a, bfr, acc, 0, 0, 0);
    }

    // ---- epilogue: atomic accumulate (out pre-initialized with bias) ----
    int co0 = cstrip * 16 + (lane >> 4) * 4;
    int wcol = T * 16 + (lane & 15);
#pragma unroll
    for (int r = 0; r < 4; ++r)
        atomicAdd(&out[((b * COUT + co0 + r) * DD_ + d) * HWs + h * WW_ + wcol], acc[r]);
}

extern "C" void kernel_launch(void* const* d_in, const int* in_sizes, int n_in,
                              void* d_out, int out_size, void* d_ws, size_t ws_size,
                              hipStream_t stream) {
    const float* x    = (const float*)d_in[0];
    const float* off  = (const float*)d_in[1];
    const float* msk  = (const float*)d_in[2];
    const float* w    = (const float*)d_in[3];
    const float* bias = (const float*)d_in[4];
    float* out = (float*)d_out;

    const size_t WF_BYTES = (size_t)KK * 4 * 64 * 8 * sizeof(_Float16);   // 110592
    const size_t XT_OFF   = 131072;
    const size_t XT_BYTES = (size_t)BSZ * DHW * CIN * sizeof(_Float16);   // 2359296

    _Float16* wf = (_Float16*)d_ws;
    _Float16* xT = (_Float16*)((char*)d_ws + XT_OFF);
    int use = (ws_size >= XT_OFF + XT_BYTES) ? 1 : 0;

    init_out<<<(BSZ * COUT * DHW / 4 + 255) / 256, 256, 0, stream>>>(bias, out);
    if (use) {
        int wblocks = (KK * 4 * 64 * 8 + 255) / 256;   // 216
        prep<<<NBLK + wblocks, 256, 0, stream>>>(x, w, xT, wf);
        dcn3d<1><<<3 * NBLK, NT, 0, stream>>>(x, xT, off, msk, w, wf, out);
    } else {
        dcn3d<0><<<3 * NBLK, NT, 0, stream>>>(x, xT, off, msk, w, wf, out);
    }
}

// Round 8
// 34.980 us; speedup vs baseline: 1.3907x; 1.3907x over previous
//
#include <hip/hip_runtime.h>
#include <hip/hip_fp16.h>

#define BSZ 2
#define CIN 32
#define COUT 64
#define DD_ 8
#define HH_ 48
#define WW_ 48
#define KK 27
#define HWs (HH_*WW_)
#define DHW (DD_*HH_*WW_)
#define NBLK (BSZ*DD_*HH_)    // 768 row-blocks
#define NT 768                // 12 waves = 12 output tiles (4 co-strips x 3 w-tiles)

typedef __attribute__((ext_vector_type(8))) _Float16 half8;
typedef __attribute__((ext_vector_type(4))) float f32x4;

__device__ __forceinline__ half8 splat_h(unsigned packed, int hi) {
    union { unsigned v; _Float16 h[2]; } c; c.v = packed;
    _Float16 e = c.h[hi];
    return (half8){e, e, e, e, e, e, e, e};
}

// prep: blocks [0,NBLK): x f32 [B][Cin][D][H][W] -> xT f16 [B][D][H][W][Cin]
//       blocks [NBLK,..): w f32 (Cout,Cin,K) -> wf f16 lane-linear A-frags:
//       wf[((k*4 + c)*64 + l)*8 + j] = w[c*16+(l&15)][(l>>4)*8+j][k]
__global__ void prep(const float* __restrict__ x, const float* __restrict__ wsrc,
                     _Float16* __restrict__ xT, _Float16* __restrict__ wf) {
    __shared__ float tile[CIN][WW_];
    int blk = blockIdx.x;
    if (blk < NBLK) {
        int h = blk % HH_;
        int t0 = blk / HH_;
        int d = t0 % DD_;
        int b = t0 / DD_;
        int base = d * HWs + h * WW_;
        for (int e = threadIdx.x; e < CIN * WW_; e += 256) {
            int ci = e / WW_, w = e - ci * WW_;
            tile[ci][w] = x[(size_t)(b * CIN + ci) * DHW + base + w];
        }
        __syncthreads();
        for (int e = threadIdx.x; e < CIN * WW_; e += 256) {
            int w = e >> 5, ci = e & 31;
            xT[(size_t)(b * DHW + base + w) * CIN + ci] = (_Float16)tile[ci][w];
        }
    } else {
        int idx = (blk - NBLK) * 256 + threadIdx.x;
        if (idx < KK * 4 * 64 * 8) {
            int j = idx & 7, l = (idx >> 3) & 63, c = (idx >> 9) & 3, k = idx >> 11;
            int co = c * 16 + (l & 15), ci = (l >> 4) * 8 + j;
            wf[idx] = (_Float16)wsrc[(co * CIN + ci) * KK + k];
        }
    }
}

template<int USE_XT>
__launch_bounds__(NT, 6)
__global__ void dcn3d(const float* __restrict__ x, const _Float16* __restrict__ xT,
                      const float* __restrict__ off, const float* __restrict__ msk,
                      const float* __restrict__ wsrc, const _Float16* __restrict__ wf,
                      const float* __restrict__ bias, float* __restrict__ out) {
    int blk = blockIdx.x;
    int h = blk % HH_;
    int t0 = blk / HH_;
    int d = t0 % DD_;
    int b = t0 / DD_;

    // params: x = sp00|sp01<<16, y = sp10|sp11<<16, z = h2(f00,f01), w = h2(f10,f11)
    __shared__ uint4 Pp[KK * WW_];          // 20736 B
    // S fragments: Sh[buf][(kl*3 + T)*64 + g*16 + wl], 16B granules
    __shared__ half8 Sh[2][7 * 3 * 64];     // 2 x 21504 B    => total 63744 B

    int tid = threadIdx.x;
    int lane = tid & 63;
    int wid = tid >> 6;
    int cstrip = wid & 3;
    int T = wid >> 2;
    int spb = d * HWs + h * WW_;

    const _Float16* xTb = xT + (size_t)b * DHW * CIN;
    const float* xb = x + (size_t)b * CIN * DHW;

    // ---- Phase A: params for all 27x48 points -> Pp (<=2 points/thread) ----
    for (int p = tid; p < KK * WW_; p += NT) {
        int k = p / WW_;
        int w = p - k * WW_;
        int kd = k / 9, kh2 = (k / 3) % 3, kw2 = k % 3;
        int dpos = d + kd - 1;
        bool vd = (dpos >= 0) && (dpos < DD_);
        int didx = min(max(dpos, 0), DD_ - 1);
        int rb = didx * HWs;
        int sp = spb + w;
        float oh = off[(b * (2 * KK) + 2 * k) * DHW + sp];
        float ow = off[(b * (2 * KK) + 2 * k + 1) * DHW + sp];
        float m  = msk[(b * KK + k) * DHW + sp];
        float vm = vd ? m : 0.f;
        float hhf = (float)(kh2 + h - 1) + oh;
        float wwf = (float)(kw2 + w - 1) + ow;
        float h0f = floorf(hhf), w0f = floorf(wwf);
        float lh = hhf - h0f, lw = wwf - w0f;
        int h0 = (int)h0f, w0 = (int)w0f, h1 = h0 + 1, w1 = w0 + 1;
        bool ih0 = (h0 >= 0) && (h0 < HH_), ih1 = (h1 >= 0) && (h1 < HH_);
        bool iw0 = (w0 >= 0) && (w0 < WW_), iw1 = (w1 >= 0) && (w1 < WW_);
        int h0c = min(max(h0, 0), HH_ - 1), h1c = min(max(h1, 0), HH_ - 1);
        int w0c = min(max(w0, 0), WW_ - 1), w1c = min(max(w1, 0), WW_ - 1);
        float f00 = (ih0 && iw0) ? (1.f - lh) * (1.f - lw) * vm : 0.f;
        float f01 = (ih0 && iw1) ? (1.f - lh) * lw * vm : 0.f;
        float f10 = (ih1 && iw0) ? lh * (1.f - lw) * vm : 0.f;
        float f11 = (ih1 && iw1) ? lh * lw * vm : 0.f;
        uint4 P;
        P.x = (unsigned)(rb + h0c * WW_ + w0c) | ((unsigned)(rb + h0c * WW_ + w1c) << 16);
        P.y = (unsigned)(rb + h1c * WW_ + w0c) | ((unsigned)(rb + h1c * WW_ + w1c) << 16);
        __half2 ha = __floats2half2_rn(f00, f01);
        __half2 hb = __floats2half2_rn(f10, f11);
        P.z = *(const unsigned*)&ha;
        P.w = *(const unsigned*)&hb;
        Pp[p] = P;
    }
    __syncthreads();

    // pipeline registers (named, never indexed)
    half8 qA00 = {}, qA01 = {}, qA10 = {}, qA11 = {};
    half8 qB00 = {}, qB01 = {}, qB10 = {}, qB11 = {};
    unsigned wzA = 0, wwA = 0, wzB = 0, wwB = 0;
    int sbA = 0, sbB = 0;
    bool vB = false;

    // task t -> p = t>>2 (local point), g = t&3 (ci granule); kl = p/48, w = p%48
#define TASK(S, T_, KB)                                                          \
    {                                                                            \
        int t = (T_);                                                            \
        int p = t >> 2, g = t & 3;                                               \
        int kl = p / WW_, w = p - kl * WW_;                                      \
        uint4 P = Pp[((KB) + kl) * WW_ + w];                                     \
        wz##S = P.z; ww##S = P.w;                                                \
        sb##S = (kl * 3 + (w >> 4)) * 64 + g * 16 + (w & 15);                    \
        if (USE_XT) {                                                            \
            const _Float16* bp = xTb + g * 8;                                    \
            q##S##00 = *(const half8*)(bp + ((size_t)(P.x & 0xFFFFu) << 5));     \
            q##S##01 = *(const half8*)(bp + ((size_t)(P.x >> 16) << 5));         \
            q##S##10 = *(const half8*)(bp + ((size_t)(P.y & 0xFFFFu) << 5));     \
            q##S##11 = *(const half8*)(bp + ((size_t)(P.y >> 16) << 5));         \
        } else {                                                                 \
            _Pragma("unroll")                                                    \
            for (int j = 0; j < 8; ++j) {                                        \
                const float* xp = xb + (size_t)(g * 8 + j) * DHW;                \
                q##S##00[j] = (_Float16)xp[P.x & 0xFFFFu];                       \
                q##S##01[j] = (_Float16)xp[P.x >> 16];                           \
                q##S##10[j] = (_Float16)xp[P.y & 0xFFFFu];                       \
                q##S##11[j] = (_Float16)xp[P.y >> 16];                           \
            }                                                                    \
        }                                                                        \
    }

#define ISSUE(NKg, KB)                                                           \
    TASK(A, tid, KB)                                                             \
    vB = tid < (NKg) * 192 - NT;                                                 \
    if (vB) TASK(B, tid + NT, KB)

#define WRITE(BUF)                                                               \
    Sh[BUF][sbA] = qA00 * splat_h(wzA, 0) + qA01 * splat_h(wzA, 1)               \
                 + qA10 * splat_h(wwA, 0) + qA11 * splat_h(wwA, 1);              \
    if (vB)                                                                      \
        Sh[BUF][sbB] = qB00 * splat_h(wzB, 0) + qB01 * splat_h(wzB, 1)           \
                     + qB10 * splat_h(wwB, 0) + qB11 * splat_h(wwB, 1);

    f32x4 acc = {0.f, 0.f, 0.f, 0.f};

#define GEMM(NKg, KB, BUF)                                                       \
    _Pragma("unroll")                                                            \
    for (int kl = 0; kl < (NKg); ++kl) {                                         \
        half8 a;                                                                 \
        if (USE_XT) {                                                            \
            a = *(const half8*)(wf + ((((KB) + kl) * 4 + cstrip) * 64 + lane) * 8); \
        } else {                                                                 \
            int co = cstrip * 16 + (lane & 15);                                  \
            int ci0 = (lane >> 4) * 8;                                           \
            _Pragma("unroll")                                                    \
            for (int j = 0; j < 8; ++j)                                          \
                a[j] = (_Float16)wsrc[(co * CIN + ci0 + j) * KK + (KB) + kl];    \
        }                                                                        \
        half8 bfr = Sh[BUF][(kl * 3 + T) * 64 + (lane >> 4) * 16 + (lane & 15)]; \
        acc = __builtin_amdgcn_mfma_f32_16x16x32_f16(a, bfr, acc, 0, 0, 0);      \
    }

    // ---- pipelined groups {7,7,7,6}: ISSUE(g+1) || GEMM(g), then WRITE(g+1) ----
    ISSUE(7, 0)
    WRITE(0)
    __syncthreads();

    ISSUE(7, 7)
    GEMM(7, 0, 0)
    WRITE(1)
    __syncthreads();

    ISSUE(7, 14)
    GEMM(7, 7, 1)
    WRITE(0)
    __syncthreads();

    ISSUE(6, 21)
    GEMM(7, 14, 0)
    WRITE(1)
    __syncthreads();

    GEMM(6, 21, 1)

#undef TASK
#undef ISSUE
#undef WRITE
#undef GEMM

    // ---- epilogue: direct store (C: col=lane&15 -> w, row=(lane>>4)*4+r -> co) ----
    int co0 = cstrip * 16 + (lane >> 4) * 4;
    int wcol = T * 16 + (lane & 15);
#pragma unroll
    for (int r = 0; r < 4; ++r)
        out[((b * COUT + co0 + r) * DD_ + d) * HWs + h * WW_ + wcol] = acc[r] + bias[co0 + r];
}

extern "C" void kernel_launch(void* const* d_in, const int* in_sizes, int n_in,
                              void* d_out, int out_size, void* d_ws, size_t ws_size,
                              hipStream_t stream) {
    const float* x    = (const float*)d_in[0];
    const float* off  = (const float*)d_in[1];
    const float* msk  = (const float*)d_in[2];
    const float* w    = (const float*)d_in[3];
    const float* bias = (const float*)d_in[4];
    float* out = (float*)d_out;

    const size_t XT_OFF   = 131072;
    const size_t XT_BYTES = (size_t)BSZ * DHW * CIN * sizeof(_Float16);   // 2359296

    _Float16* wf = (_Float16*)d_ws;
    _Float16* xT = (_Float16*)((char*)d_ws + XT_OFF);
    int use = (ws_size >= XT_OFF + XT_BYTES) ? 1 : 0;

    if (use) {
        int wblocks = (KK * 4 * 64 * 8 + 255) / 256;   // 216
        prep<<<NBLK + wblocks, 256, 0, stream>>>(x, w, xT, wf);
        dcn3d<1><<<NBLK, NT, 0, stream>>>(x, xT, off, msk, w, wf, bias, out);
    } else {
        dcn3d<0><<<NBLK, NT, 0, stream>>>(x, xT, off, msk, w, wf, bias, out);
    }
}